// Round 23
// baseline (40.946 us; speedup 1.0000x reference)
//
#include <hip/hip_runtime.h>
#include <math.h>

#define TT 1024
#define DD 128

static constexpr float kNegInf = -1e9f;

typedef __fp16 h2 __attribute__((ext_vector_type(2)));

__device__ __forceinline__ unsigned int pk16(float a, float b) {
  h2 v = __builtin_amdgcn_cvt_pkrtz(a, b);
  return __builtin_bit_cast(unsigned int, v);
}
__device__ __forceinline__ unsigned int pkrne(float a, float b) {
  h2 v; v.x = (__fp16)a; v.y = (__fp16)b;
  return __builtin_bit_cast(unsigned int, v);
}
__device__ __forceinline__ float dot2f(unsigned int a, unsigned int b, float c) {
#if __has_builtin(__builtin_amdgcn_fdot2)
  return __builtin_amdgcn_fdot2(__builtin_bit_cast(h2, a),
                                __builtin_bit_cast(h2, b), c, false);
#else
  h2 av = __builtin_bit_cast(h2, a), bv = __builtin_bit_cast(h2, b);
  return c + (float)av.x * (float)bv.x + (float)av.y * (float)bv.y;
#endif
}
__device__ __forceinline__ float absdot(unsigned int a, unsigned int b, float c) {
  h2 d = __builtin_bit_cast(h2, a) - __builtin_bit_cast(h2, b);
  unsigned int ad = __builtin_bit_cast(unsigned int, d) & 0x7FFF7FFFu;
  return dot2f(ad, 0x3C003C00u, c);
}

// ---- K0: prep, 8 j-rows per block, 256 blocks ----
__global__ __launch_bounds__(256) void k_prep(const float* __restrict__ h,
                                              const float* __restrict__ w,
                                              const int* __restrict__ mk,
                                              unsigned int* __restrict__ hTd16,
                                              unsigned int* __restrict__ hT16,
                                              float* __restrict__ swj,
                                              float* __restrict__ bias) {
  __shared__ __align__(16) float tile[8][132];
  const int b   = blockIdx.x >> 7;
  const int jt8 = blockIdx.x & 127;          // 8-row tile index
  const int tid = threadIdx.x;
  // load 8 rows x 128 d = 256 float4
  {
    const float4 v = ((const float4*)h)[(size_t)(b * TT + jt8 * 8) * 32 + tid];
    const int j = tid >> 5, c = tid & 31;
    *((float4*)&tile[j][c * 4]) = v;
  }
  __syncthreads();
  // hTd16[d2][j]: 64 d2 x 8 j = 512 words, 2 per thread
#pragma unroll
  for (int k = 0; k < 2; ++k) {
    int idx = k * 256 + tid;                 // 0..511
    int d2 = idx >> 3, jl = idx & 7;
    hTd16[((size_t)(b * 64 + d2)) * TT + jt8 * 8 + jl] =
        pkrne(tile[jl][2 * d2], tile[jl][2 * d2 + 1]);
  }
  // hT16[jp][d]: 4 jp x 128 d = 512 words, 2 per thread
#pragma unroll
  for (int k = 0; k < 2; ++k) {
    int idx = k * 256 + tid;                 // 0..511
    int jp = idx >> 7, d = idx & 127;
    hT16[((size_t)(b * 512 + jt8 * 4 + jp)) * DD + d] =
        pk16(tile[jp * 2][d], tile[jp * 2 + 1][d]);
  }
  // wj: thread = (row jl 0..7) x (dim-32nd t 0..31); 32-lane shuffle reduce
  {
    const int jl = tid >> 5, t = tid & 31;
    const float4 hv = *(const float4*)&tile[jl][t * 4];
    const float4 wv = *(const float4*)&w[t * 4];
    float p = hv.x * wv.x + hv.y * wv.y + hv.z * wv.z + hv.w * wv.w;
#pragma unroll
    for (int off = 16; off; off >>= 1) p += __shfl_xor(p, off);
    if (t == 0) {
      const int row = b * TT + jt8 * 8 + jl;
      const bool ok = (mk[row] != 0);
      swj[row]  = ok ? -p : 0.f;
      bias[row] = ok ? 0.f : kNegInf;
    }
  }
}

// ---- K1: block = 8 rows x FULL 1024 j; 512 thr; f16-pk distance ----
// launch_bounds(512, 6): 3 blocks/CU (12 waves/CU), VGPR cap ~85.
__global__ __launch_bounds__(512, 6) void k_fused(
    const float* __restrict__ h, const unsigned int* __restrict__ hTd16,
    const unsigned int* __restrict__ hT16,
    const float* __restrict__ swj, const float* __restrict__ bias,
    float* __restrict__ out) {
  __shared__ __align__(16) unsigned int A16[8][64];  // 2 KB [row][d2]
  __shared__ __align__(16) unsigned int Pt[512][8];  // 16 KB [jp][row]
  __shared__ __align__(16) float ctxp[4][8][DD];     // 16 KB [slice][row][d]
  __shared__ float redm[8][4];
  __shared__ float redl[8][4];

  const int tid  = threadIdx.x;
  const int lane = tid & 63;
  const int wv   = tid >> 6;                // 0..7
  const int rh   = tid >> 8;                // row-half 0/1
  const int b    = blockIdx.x >> 7;
  const int row0 = (blockIdx.x & 127) * 8;
  const int rot  = blockIdx.x & 15;

  // stage 8 A-rows as f16 dim-pair words (one word per thread)
  {
    const int r = tid >> 6, d2 = tid & 63;
    const float2 av =
        *(const float2*)(h + ((size_t)b * TT + row0 + r) * DD + 2 * d2);
    A16[r][d2] = pkrne(av.x, av.y);
  }
  __syncthreads();

  // ---------------- phase 1: distances, f16-pk, J=4 x R=4, dbuf ---------
  const int q = tid & 255;                  // j-quad id
  const int j = q * 4;
  const unsigned int* Bb = hTd16 + (size_t)b * 64 * TT + j;
  const int ar = rh * 4;
  float acc[4][4];
#pragma unroll
  for (int u = 0; u < 4; ++u)
#pragma unroll
    for (int r = 0; r < 4; ++r) acc[u][r] = 0.f;

#define PS(s) (((s) + rot) & 15)

#define LOADB16(B, s) {                                       \
    B[0] = *(const uint4*)(Bb + (size_t)((s) * 4 + 0) * TT);  \
    B[1] = *(const uint4*)(Bb + (size_t)((s) * 4 + 1) * TT);  \
    B[2] = *(const uint4*)(Bb + (size_t)((s) * 4 + 2) * TT);  \
    B[3] = *(const uint4*)(Bb + (size_t)((s) * 4 + 3) * TT); }

#define COMP16(B, s) {                                                 \
    _Pragma("unroll") for (int r = 0; r < 4; ++r) {                    \
      const uint4 aw = *(const uint4*)&A16[ar + r][(s) * 4];           \
      _Pragma("unroll") for (int dl = 0; dl < 4; ++dl) {               \
        const unsigned int a = (dl == 0) ? aw.x : (dl == 1) ? aw.y     \
                               : (dl == 2) ? aw.z : aw.w;              \
        acc[0][r] = absdot(a, B[dl].x, acc[0][r]);                     \
        acc[1][r] = absdot(a, B[dl].y, acc[1][r]);                     \
        acc[2][r] = absdot(a, B[dl].z, acc[2][r]);                     \
        acc[3][r] = absdot(a, B[dl].w, acc[3][r]);                     \
      } } }

  {
    uint4 B0[4], B1[4];
    LOADB16(B0, PS(0));
#pragma unroll 1
    for (int s = 0; s < 8; ++s) {
      const int p1 = PS(2 * s + 1);
      const int p0 = PS(2 * s);
      LOADB16(B1, p1);                   // unconditional
      COMP16(B0, p0);
      if (s < 7) LOADB16(B0, PS(2 * s + 2));
      COMP16(B1, p1);
    }
  }

  // scores
  const float4 swv = *(const float4*)(swj + (size_t)b * TT + j);
  const float4 bvv = *(const float4*)(bias + (size_t)b * TT + j);
  float sc[4][4];
#pragma unroll
  for (int r = 0; r < 4; ++r) {
    sc[0][r] = fmaf(swv.x, acc[0][r], bvv.x);
    sc[1][r] = fmaf(swv.y, acc[1][r], bvv.y);
    sc[2][r] = fmaf(swv.z, acc[2][r], bvv.z);
    sc[3][r] = fmaf(swv.w, acc[3][r], bvv.w);
  }

  // row max over full 1024 j (4 waves per row-half)
  {
    float mr[4];
#pragma unroll
    for (int r = 0; r < 4; ++r) {
      float m0 = fmaxf(fmaxf(sc[0][r], sc[1][r]), fmaxf(sc[2][r], sc[3][r]));
#pragma unroll
      for (int off = 32; off; off >>= 1) m0 = fmaxf(m0, __shfl_xor(m0, off));
      mr[r] = m0;
    }
    if (lane == 0) {
#pragma unroll
      for (int r = 0; r < 4; ++r) redm[wv][r] = mr[r];
    }
  }
  __syncthreads();
  float M[4];
#pragma unroll
  for (int r = 0; r < 4; ++r)
    M[r] = fmaxf(fmaxf(redm[rh * 4 + 0][r], redm[rh * 4 + 1][r]),
                 fmaxf(redm[rh * 4 + 2][r], redm[rh * 4 + 3][r]));

  // exp + pack P j-pairs + sums
  {
    float p[4][4];
    float ls[4] = {0.f, 0.f, 0.f, 0.f};
#pragma unroll
    for (int u = 0; u < 4; ++u)
#pragma unroll
      for (int r = 0; r < 4; ++r) {
        p[u][r] = __expf(sc[u][r] - M[r]);
        ls[r] += p[u][r];
      }
    uint4 w0 = {pk16(p[0][0], p[1][0]), pk16(p[0][1], p[1][1]),
                pk16(p[0][2], p[1][2]), pk16(p[0][3], p[1][3])};
    uint4 w1 = {pk16(p[2][0], p[3][0]), pk16(p[2][1], p[3][1]),
                pk16(p[2][2], p[3][2]), pk16(p[2][3], p[3][3])};
    *(uint4*)&Pt[2 * q + 0][rh * 4] = w0;
    *(uint4*)&Pt[2 * q + 1][rh * 4] = w1;
#pragma unroll
    for (int r = 0; r < 4; ++r) {
#pragma unroll
      for (int off = 32; off; off >>= 1) ls[r] += __shfl_xor(ls[r], off);
    }
    if (lane == 0) {
#pragma unroll
      for (int r = 0; r < 4; ++r) redl[wv][r] = ls[r];
    }
  }
  __syncthreads();

  // ---------------- PV: thread = (dpair, rowhalf, slice 0..3) ------------
  const int dp  = tid & 63;
  const int rh2 = (tid >> 6) & 1;
  const int s   = tid >> 7;                 // 0..3, 128 jp each
  const unsigned int* Vp =
      hT16 + ((size_t)(b * 512 + s * 128)) * DD + dp * 2;
  float cx[4][2];
#pragma unroll
  for (int r = 0; r < 4; ++r) { cx[r][0] = 0.f; cx[r][1] = 0.f; }
  const int qrot = rot * 8;
#pragma unroll 4
  for (int qq = 0; qq < 128; ++qq) {
    const int qi = (qq + qrot) & 127;
    const uint4 P = *(const uint4*)&Pt[s * 128 + qi][rh2 * 4];
    const uint2 V = *(const uint2*)(Vp + (size_t)qi * DD);
    cx[0][0] = dot2f(P.x, V.x, cx[0][0]); cx[0][1] = dot2f(P.x, V.y, cx[0][1]);
    cx[1][0] = dot2f(P.y, V.x, cx[1][0]); cx[1][1] = dot2f(P.y, V.y, cx[1][1]);
    cx[2][0] = dot2f(P.z, V.x, cx[2][0]); cx[2][1] = dot2f(P.z, V.y, cx[2][1]);
    cx[3][0] = dot2f(P.w, V.x, cx[3][0]); cx[3][1] = dot2f(P.w, V.y, cx[3][1]);
  }
#pragma unroll
  for (int r = 0; r < 4; ++r)
    *(float2*)&ctxp[s][rh2 * 4 + r][dp * 2] = make_float2(cx[r][0], cx[r][1]);
  __syncthreads();

  // ---------------- epilogue: reduce slices, normalize, concat ----------
#pragma unroll
  for (int k = 0; k < 2; ++k) {
    const int idx = tid + k * 512;        // 0..1023
    const int r = idx >> 7, d = idx & 127;
    const int hb = (r >> 2) * 4, rr = r & 3;
    const float L = redl[hb + 0][rr] + redl[hb + 1][rr] +
                    redl[hb + 2][rr] + redl[hb + 3][rr];
    const float c = (ctxp[0][r][d] + ctxp[1][r][d]) +
                    (ctxp[2][r][d] + ctxp[3][r][d]);
    const size_t row = (size_t)blockIdx.x * 8 + r;
    out[row * 256 + d]       = h[row * DD + d];
    out[row * 256 + 128 + d] = c / L;
  }
}

extern "C" void kernel_launch(void* const* d_in, const int* in_sizes, int n_in,
                              void* d_out, int out_size, void* d_ws, size_t ws_size,
                              hipStream_t stream) {
  const float* h  = (const float*)d_in[0];
  const int*   mk = (const int*)d_in[1];
  const float* w  = (const float*)d_in[2];
  float* out = (float*)d_out;

  char* ws = (char*)d_ws;
  float*        swj   = (float*)ws;                              // 8 KB
  float*        bias  = (float*)(ws + 8192);                     // 8 KB
  unsigned int* hTd16 = (unsigned int*)(ws + 16384);             // 512 KB
  unsigned int* hT16  = (unsigned int*)(ws + 16384 + 524288);    // 512 KB

  hipLaunchKernelGGL(k_prep,  dim3(256), dim3(256), 0, stream,
                     h, w, mk, hTd16, hT16, swj, bias);
  hipLaunchKernelGGL(k_fused, dim3(256), dim3(512), 0, stream,
                     h, hTd16, hT16, swj, bias, out);
}

// Round 24
// 35.525 us; speedup vs baseline: 1.1526x; 1.1526x over previous
//
#include <hip/hip_runtime.h>
#include <math.h>

#define TT 1024
#define DD 128

static constexpr float kNegInf = -1e9f;

typedef __fp16 h2 __attribute__((ext_vector_type(2)));

__device__ __forceinline__ unsigned int pk16(float a, float b) {
  h2 v = __builtin_amdgcn_cvt_pkrtz(a, b);
  return __builtin_bit_cast(unsigned int, v);
}
__device__ __forceinline__ unsigned int pkrne(float a, float b) {
  h2 v; v.x = (__fp16)a; v.y = (__fp16)b;
  return __builtin_bit_cast(unsigned int, v);
}
__device__ __forceinline__ float dot2f(unsigned int a, unsigned int b, float c) {
#if __has_builtin(__builtin_amdgcn_fdot2)
  return __builtin_amdgcn_fdot2(__builtin_bit_cast(h2, a),
                                __builtin_bit_cast(h2, b), c, false);
#else
  h2 av = __builtin_bit_cast(h2, a), bv = __builtin_bit_cast(h2, b);
  return c + (float)av.x * (float)bv.x + (float)av.y * (float)bv.y;
#endif
}
__device__ __forceinline__ float absdot(unsigned int a, unsigned int b, float c) {
  h2 d = __builtin_bit_cast(h2, a) - __builtin_bit_cast(h2, b);
  unsigned int ad = __builtin_bit_cast(unsigned int, d) & 0x7FFF7FFFu;
  return dot2f(ad, 0x3C003C00u, c);
}

// ---- K0: prep, 8 j-rows per block, 256 blocks ----
__global__ __launch_bounds__(256) void k_prep(const float* __restrict__ h,
                                              const float* __restrict__ w,
                                              const int* __restrict__ mk,
                                              unsigned int* __restrict__ hTd16,
                                              unsigned int* __restrict__ hT16,
                                              float* __restrict__ swj,
                                              float* __restrict__ bias) {
  __shared__ __align__(16) float tile[8][132];
  const int b   = blockIdx.x >> 7;
  const int jt8 = blockIdx.x & 127;          // 8-row tile index
  const int tid = threadIdx.x;
  // load 8 rows x 128 d = 256 float4
  {
    const float4 v = ((const float4*)h)[(size_t)(b * TT + jt8 * 8) * 32 + tid];
    const int j = tid >> 5, c = tid & 31;
    *((float4*)&tile[j][c * 4]) = v;
  }
  __syncthreads();
  // hTd16[d2][j]: 64 d2 x 8 j = 512 words, 2 per thread
#pragma unroll
  for (int k = 0; k < 2; ++k) {
    int idx = k * 256 + tid;                 // 0..511
    int d2 = idx >> 3, jl = idx & 7;
    hTd16[((size_t)(b * 64 + d2)) * TT + jt8 * 8 + jl] =
        pkrne(tile[jl][2 * d2], tile[jl][2 * d2 + 1]);
  }
  // hT16[jp][d]: 4 jp x 128 d = 512 words, 2 per thread
#pragma unroll
  for (int k = 0; k < 2; ++k) {
    int idx = k * 256 + tid;                 // 0..511
    int jp = idx >> 7, d = idx & 127;
    hT16[((size_t)(b * 512 + jt8 * 4 + jp)) * DD + d] =
        pk16(tile[jp * 2][d], tile[jp * 2 + 1][d]);
  }
  // wj: thread = (row jl 0..7) x (dim-32nd t 0..31); 32-lane shuffle reduce
  {
    const int jl = tid >> 5, t = tid & 31;
    const float4 hv = *(const float4*)&tile[jl][t * 4];
    const float4 wv = *(const float4*)&w[t * 4];
    float p = hv.x * wv.x + hv.y * wv.y + hv.z * wv.z + hv.w * wv.w;
#pragma unroll
    for (int off = 16; off; off >>= 1) p += __shfl_xor(p, off);
    if (t == 0) {
      const int row = b * TT + jt8 * 8 + jl;
      const bool ok = (mk[row] != 0);
      swj[row]  = ok ? -p : 0.f;
      bias[row] = ok ? 0.f : kNegInf;
    }
  }
}

// ---- K1: block = 8 rows x FULL 1024 j; 512 thr; f16-pk distance ----
__global__ __launch_bounds__(512, 2) void k_fused(
    const float* __restrict__ h, const unsigned int* __restrict__ hTd16,
    const unsigned int* __restrict__ hT16,
    const float* __restrict__ swj, const float* __restrict__ bias,
    float* __restrict__ out) {
  __shared__ __align__(16) unsigned int A16[8][64];  // 2 KB [row][d2]
  __shared__ __align__(16) unsigned int Pt[512][8];  // 16 KB [jp][row]
  __shared__ __align__(16) float ctxp[4][8][DD];     // 16 KB [slice][row][d]
  __shared__ float redm[8][4];
  __shared__ float redl[8][4];

  const int tid  = threadIdx.x;
  const int lane = tid & 63;
  const int wv   = tid >> 6;                // 0..7
  const int rh   = tid >> 8;                // row-half 0/1
  const int b    = blockIdx.x >> 7;
  const int row0 = (blockIdx.x & 127) * 8;
  const int rot  = blockIdx.x & 15;

  // stage 8 A-rows as f16 dim-pair words (one word per thread)
  {
    const int r = tid >> 6, d2 = tid & 63;
    const float2 av =
        *(const float2*)(h + ((size_t)b * TT + row0 + r) * DD + 2 * d2);
    A16[r][d2] = pkrne(av.x, av.y);
  }
  __syncthreads();

  // ---------------- phase 1: distances, f16-pk, J=4 x R=4, dbuf ---------
  const int q = tid & 255;                  // j-quad id
  const int j = q * 4;
  const unsigned int* Bb = hTd16 + (size_t)b * 64 * TT + j;
  const int ar = rh * 4;
  float acc[4][4];                          // [u(j)][r(row)]
#pragma unroll
  for (int u = 0; u < 4; ++u)
#pragma unroll
    for (int r = 0; r < 4; ++r) acc[u][r] = 0.f;

#define PS(s) (((s) + rot) & 15)

#define LOADB16(B, s) {                                       \
    B[0] = *(const uint4*)(Bb + (size_t)((s) * 4 + 0) * TT);  \
    B[1] = *(const uint4*)(Bb + (size_t)((s) * 4 + 1) * TT);  \
    B[2] = *(const uint4*)(Bb + (size_t)((s) * 4 + 2) * TT);  \
    B[3] = *(const uint4*)(Bb + (size_t)((s) * 4 + 3) * TT); }

#define COMP16(B, s) {                                                 \
    _Pragma("unroll") for (int r = 0; r < 4; ++r) {                    \
      const uint4 aw = *(const uint4*)&A16[ar + r][(s) * 4];           \
      _Pragma("unroll") for (int dl = 0; dl < 4; ++dl) {               \
        const unsigned int a = (dl == 0) ? aw.x : (dl == 1) ? aw.y     \
                               : (dl == 2) ? aw.z : aw.w;              \
        acc[0][r] = absdot(a, B[dl].x, acc[0][r]);                     \
        acc[1][r] = absdot(a, B[dl].y, acc[1][r]);                     \
        acc[2][r] = absdot(a, B[dl].z, acc[2][r]);                     \
        acc[3][r] = absdot(a, B[dl].w, acc[3][r]);                     \
      } } }

  {
    uint4 B0[4], B1[4];
    LOADB16(B0, PS(0));
#pragma unroll 1
    for (int s = 0; s < 8; ++s) {
      const int p1 = PS(2 * s + 1);
      const int p0 = PS(2 * s);
      LOADB16(B1, p1);                   // unconditional
      COMP16(B0, p0);
      if (s < 7) LOADB16(B0, PS(2 * s + 2));
      COMP16(B1, p1);
    }
  }

  // scores
  const float4 swv = *(const float4*)(swj + (size_t)b * TT + j);
  const float4 bvv = *(const float4*)(bias + (size_t)b * TT + j);
  float sc[4][4];
#pragma unroll
  for (int r = 0; r < 4; ++r) {
    sc[0][r] = fmaf(swv.x, acc[0][r], bvv.x);
    sc[1][r] = fmaf(swv.y, acc[1][r], bvv.y);
    sc[2][r] = fmaf(swv.z, acc[2][r], bvv.z);
    sc[3][r] = fmaf(swv.w, acc[3][r], bvv.w);
  }

  // row max over full 1024 j (4 waves per row-half)
  {
    float mr[4];
#pragma unroll
    for (int r = 0; r < 4; ++r) {
      float m0 = fmaxf(fmaxf(sc[0][r], sc[1][r]), fmaxf(sc[2][r], sc[3][r]));
#pragma unroll
      for (int off = 32; off; off >>= 1) m0 = fmaxf(m0, __shfl_xor(m0, off));
      mr[r] = m0;
    }
    if (lane == 0) {
#pragma unroll
      for (int r = 0; r < 4; ++r) redm[wv][r] = mr[r];
    }
  }
  __syncthreads();
  float M[4];
#pragma unroll
  for (int r = 0; r < 4; ++r)
    M[r] = fmaxf(fmaxf(redm[rh * 4 + 0][r], redm[rh * 4 + 1][r]),
                 fmaxf(redm[rh * 4 + 2][r], redm[rh * 4 + 3][r]));

  // exp + pack P j-pairs + sums
  {
    float p[4][4];
    float ls[4] = {0.f, 0.f, 0.f, 0.f};
#pragma unroll
    for (int u = 0; u < 4; ++u)
#pragma unroll
      for (int r = 0; r < 4; ++r) {
        p[u][r] = __expf(sc[u][r] - M[r]);
        ls[r] += p[u][r];
      }
    uint4 w0 = {pk16(p[0][0], p[1][0]), pk16(p[0][1], p[1][1]),
                pk16(p[0][2], p[1][2]), pk16(p[0][3], p[1][3])};
    uint4 w1 = {pk16(p[2][0], p[3][0]), pk16(p[2][1], p[3][1]),
                pk16(p[2][2], p[3][2]), pk16(p[2][3], p[3][3])};
    *(uint4*)&Pt[2 * q + 0][rh * 4] = w0;
    *(uint4*)&Pt[2 * q + 1][rh * 4] = w1;
#pragma unroll
    for (int r = 0; r < 4; ++r) {
#pragma unroll
      for (int off = 32; off; off >>= 1) ls[r] += __shfl_xor(ls[r], off);
    }
    if (lane == 0) {
#pragma unroll
      for (int r = 0; r < 4; ++r) redl[wv][r] = ls[r];
    }
  }
  __syncthreads();

  // ---------------- PV: thread = (dpair, rowhalf, slice 0..3) ------------
  const int dp  = tid & 63;
  const int rh2 = (tid >> 6) & 1;
  const int s   = tid >> 7;                 // 0..3, 128 jp each
  const unsigned int* Vp =
      hT16 + ((size_t)(b * 512 + s * 128)) * DD + dp * 2;
  float cx[4][2];
#pragma unroll
  for (int r = 0; r < 4; ++r) { cx[r][0] = 0.f; cx[r][1] = 0.f; }
  const int qrot = rot * 8;
#pragma unroll 4
  for (int qq = 0; qq < 128; ++qq) {
    const int qi = (qq + qrot) & 127;
    const uint4 P = *(const uint4*)&Pt[s * 128 + qi][rh2 * 4];
    const uint2 V = *(const uint2*)(Vp + (size_t)qi * DD);
    cx[0][0] = dot2f(P.x, V.x, cx[0][0]); cx[0][1] = dot2f(P.x, V.y, cx[0][1]);
    cx[1][0] = dot2f(P.y, V.x, cx[1][0]); cx[1][1] = dot2f(P.y, V.y, cx[1][1]);
    cx[2][0] = dot2f(P.z, V.x, cx[2][0]); cx[2][1] = dot2f(P.z, V.y, cx[2][1]);
    cx[3][0] = dot2f(P.w, V.x, cx[3][0]); cx[3][1] = dot2f(P.w, V.y, cx[3][1]);
  }
#pragma unroll
  for (int r = 0; r < 4; ++r)
    *(float2*)&ctxp[s][rh2 * 4 + r][dp * 2] = make_float2(cx[r][0], cx[r][1]);
  __syncthreads();

  // ---------------- epilogue: reduce slices, normalize, concat ----------
#pragma unroll
  for (int k = 0; k < 2; ++k) {
    const int idx = tid + k * 512;        // 0..1023
    const int r = idx >> 7, d = idx & 127;
    const int hb = (r >> 2) * 4, rr = r & 3;
    const float L = redl[hb + 0][rr] + redl[hb + 1][rr] +
                    redl[hb + 2][rr] + redl[hb + 3][rr];
    const float c = (ctxp[0][r][d] + ctxp[1][r][d]) +
                    (ctxp[2][r][d] + ctxp[3][r][d]);
    const size_t row = (size_t)blockIdx.x * 8 + r;
    out[row * 256 + d]       = h[row * DD + d];
    out[row * 256 + 128 + d] = c / L;
  }
}

extern "C" void kernel_launch(void* const* d_in, const int* in_sizes, int n_in,
                              void* d_out, int out_size, void* d_ws, size_t ws_size,
                              hipStream_t stream) {
  const float* h  = (const float*)d_in[0];
  const int*   mk = (const int*)d_in[1];
  const float* w  = (const float*)d_in[2];
  float* out = (float*)d_out;

  char* ws = (char*)d_ws;
  float*        swj   = (float*)ws;                              // 8 KB
  float*        bias  = (float*)(ws + 8192);                     // 8 KB
  unsigned int* hTd16 = (unsigned int*)(ws + 16384);             // 512 KB
  unsigned int* hT16  = (unsigned int*)(ws + 16384 + 524288);    // 512 KB

  hipLaunchKernelGGL(k_prep,  dim3(256), dim3(256), 0, stream,
                     h, w, mk, hTd16, hT16, swj, bias);
  hipLaunchKernelGGL(k_fused, dim3(256), dim3(512), 0, stream,
                     h, hTd16, hT16, swj, bias, out);
}